// Round 7
// baseline (512.387 us; speedup 1.0000x reference)
//
#include <hip/hip_runtime.h>
#include <cstddef>

constexpr int H  = 512;   // hidden
constexpr int F  = 21;    // features
constexpr int T  = 28;    // output steps
constexpr int PB = 128;   // producer blocks
constexpr int NB = PB + 1;// + 1 dedicated y-writer block
constexpr int NT = 256;   // 4 waves/block -> 512 producer waves, 1 row/wave
constexpr int NW = NT / 64;
constexpr int KR = 4;     // poll-target replicas (sharded per WAVE now)
constexpr int PH = 3 + 3 * T;  // 87 step-unique phase arrays

#define SCOPE_AGENT __HIP_MEMORY_SCOPE_AGENT

// R7: BARRIER-FREE hops. Sentinel protocol as R6 (slot = fp32, +0.0f =
// empty; publish = plain agent-scope store to KR replicas; step-unique
// phase arrays; bank parity + self-re-poison for graph replays).
// NEW: consumers no longer stage to LDS. fma8 lane l consumes exactly rows
// l*8..l*8+7 (32B, 16B-aligned), so each lane DIRECT-POLLS its own 32B via
// two dwordx4(sc1) in one asm block. This removes the per-hop LDS write +
// __syncthreads + LDS read; the 4 waves of a block run the whole decoder
// with ZERO intra-block synchronization. Poll sharding is per-wave
// (sh=(bid*NW+w)&3) so per-replica reader count stays ~129 (R6 level).
__device__ __align__(16) float g_hs[KR][2][PH][H];
__device__ unsigned g_epoch;

// phase ids: enc_h0=0, enc_h1=1, enc_out=2, S0(t)=3+3t, S1(t)=4+3t, S2(t)=5+3t
__device__ __forceinline__ int phS0(int t) { return 3 + 3 * t; }
__device__ __forceinline__ int phS1(int t) { return 4 + 3 * t; }
__device__ __forceinline__ int phS2(int t) { return 5 + 3 * t; }

struct P {
  const float *x, *py, *eW0, *eW1, *eW2, *ebih, *ebhh;
  const float *dW0, *dW1, *dW2, *dWhh, *dbih, *dbhh, *outW, *outb;
  float* out;
};

__device__ __forceinline__ float sigm(float v)  { return 1.0f / (1.0f + __expf(-v)); }
__device__ __forceinline__ float tanh_f(float v){ return 1.0f - 2.0f / (__expf(2.0f * v) + 1.0f); }

__device__ __forceinline__ float4 wredsum4(float4 v) {
#pragma unroll
  for (int off = 32; off > 0; off >>= 1) {
    v.x += __shfl_xor(v.x, off, 64);
    v.y += __shfl_xor(v.y, off, 64);
    v.z += __shfl_xor(v.z, off, 64);
    v.w += __shfl_xor(v.w, off, 64);
  }
  return v;
}
__device__ __forceinline__ float wredsum1(float v) {
#pragma unroll
  for (int off = 32; off > 0; off >>= 1) v += __shfl_xor(v, off, 64);
  return v;
}

// Publish one row value to all KR shard replicas of phase ph (bank par).
__device__ __forceinline__ void pput4(int par, int ph, int r, float v) {
#pragma unroll
  for (int k = 0; k < KR; ++k)
    __hip_atomic_store(&g_hs[k][par][ph][r], v, __ATOMIC_RELAXED, SCOPE_AGENT);
}

typedef unsigned int u32x4 __attribute__((ext_vector_type(4)));

// Per-lane direct poll: lane reads ITS 32B slice (rows lane*8..lane*8+7) of
// phase array A with two coherent dwordx4 in one asm block (single vmcnt).
// Loops until all 8 values are non-sentinel. Divergent loop: finished lanes
// stop issuing. FRESH values each round (R3 lesson).
__device__ __forceinline__ void poll8(const float* __restrict__ A, int lane,
                                      float4& x0, float4& x1) {
  const float* q = A + lane * 8;
  u32x4 a, b;
  int guard = 0;
  bool bad;
  do {
    asm volatile("global_load_dwordx4 %0, %2, off sc1\n\t"
                 "global_load_dwordx4 %1, %2, off offset:16 sc1\n\t"
                 "s_waitcnt vmcnt(0)"
                 : "=v"(a), "=v"(b) : "v"(q) : "memory");
    bad = (a.x == 0u) | (a.y == 0u) | (a.z == 0u) | (a.w == 0u) |
          (b.x == 0u) | (b.y == 0u) | (b.z == 0u) | (b.w == 0u);
  } while (bad && ++guard < (1 << 20));
  x0 = make_float4(__uint_as_float(a.x), __uint_as_float(a.y),
                   __uint_as_float(a.z), __uint_as_float(a.w));
  x1 = make_float4(__uint_as_float(b.x), __uint_as_float(b.y),
                   __uint_as_float(b.z), __uint_as_float(b.w));
}

// 4-gate weight fragment block: 8 float4 = 128B/lane per matrix row-set.
struct W8 { float4 a[4]; float4 b[4]; };

__device__ __forceinline__ W8 ldw_g(const float* __restrict__ W, int r, int lane) {
  W8 o;
#pragma unroll
  for (int g = 0; g < 4; ++g) {
    const float* q = W + (size_t)(g * H + r) * H + lane * 8;
    o.a[g] = *(const float4*)q;
    o.b[g] = *(const float4*)(q + 4);
  }
  return o;
}
__device__ __forceinline__ W8 ldw_lds(const float* sM, int w, int lane) {
  W8 o;
#pragma unroll
  for (int g = 0; g < 4; ++g) {
    const float* q = sM + (w * 4 + g) * H + lane * 8;
    o.a[g] = *(const float4*)q;
    o.b[g] = *(const float4*)(q + 4);
  }
  return o;
}
__device__ __forceinline__ void fma8(const W8& wt, const float4& x0, const float4& x1,
                                     float s[4]) {
#pragma unroll
  for (int g = 0; g < 4; ++g) {
    s[g] += wt.a[g].x * x0.x + wt.a[g].y * x0.y + wt.a[g].z * x0.z + wt.a[g].w * x0.w
          + wt.b[g].x * x1.x + wt.b[g].y * x1.y + wt.b[g].z * x1.z + wt.b[g].w * x1.w;
  }
}

__device__ __forceinline__ float cellup(const float4& v, const float b[4], float& c) {
  float cn = sigm(v.y + b[1]) * c + sigm(v.x + b[0]) * tanh_f(v.z + b[2]);
  c = cn;
  return sigm(v.w + b[3]) * tanh_f(cn);
}

__device__ __forceinline__ void write_y_frag(const P& p, int trow, int w, int lane,
                                             const float4& h0, const float4& h1,
                                             const float* sYe) {
  for (int j = w; j < F; j += NW) {
    const float* q = p.outW + (size_t)j * (2 * H) + lane * 8;
    float4 w0 = *(const float4*)q;
    float4 w1 = *(const float4*)(q + 4);
    float s = w0.x * h0.x + w0.y * h0.y + w0.z * h0.z + w0.w * h0.w
            + w1.x * h1.x + w1.y * h1.y + w1.z * h1.z + w1.w * h1.w;
    s = wredsum1(s);
    if (lane == 0) p.out[trow * F + j] = s + sYe[j];
  }
}

__global__ __launch_bounds__(NT, 1)
void k_flow(P p) {
  const int lane = threadIdx.x & 63;
  const int w    = threadIdx.x >> 6;
  const int sh   = (blockIdx.x * NW + w) & (KR - 1);  // per-WAVE poll shard
  const unsigned ep =
      __hip_atomic_load(&g_epoch, __ATOMIC_RELAXED, SCOPE_AGENT);
  const int par = (int)(ep & 1u);           // active slot bank this dispatch

  __shared__ float sM[NW * 4 * H];   // 32 KB: producer rows of M = dW0[:,:F]@outW_h
  __shared__ float sYe[F + 3];       // y_e = outW_e@enc + outb

  if (blockIdx.x == PB) {
    // ================= Dedicated y-writer block (off critical path) ========
    float4 e0, e1;
    poll8(g_hs[sh][par][2], lane, e0, e1);
    for (int j = w; j < F; j += NW) {
      const float* q = p.outW + (size_t)j * (2 * H) + H + lane * 8;
      float4 w0 = *(const float4*)q;
      float4 w1 = *(const float4*)(q + 4);
      float s = w0.x * e0.x + w0.y * e0.y + w0.z * e0.z + w0.w * e0.w
              + w1.x * e1.x + w1.y * e1.y + w1.z * e1.z + w1.w * e1.w;
      s = wredsum1(s);
      if (lane == 0) sYe[j] = s + p.outb[j];
    }
    __syncthreads();  // sYe visible to all waves (read-only afterwards)
    for (int t = 0; t < T; ++t) {
      float4 h20, h21;
      poll8(g_hs[sh][par][phS2(t)], lane, h20, h21);
      write_y_frag(p, t, w, lane, h20, h21, sYe);
    }
    // Epoch bump: next dispatch (stream-serialized) flips the slot bank.
    if (threadIdx.x == 0)
      __hip_atomic_fetch_add(&g_epoch, 1u, __ATOMIC_RELAXED, SCOPE_AGENT);
  } else {
    // ========================= Producer blocks =============================
    const int r = blockIdx.x * NW + w;  // 1 row/wave, fixed mapping (L2 locality)

    float c0 = 0.f, c1 = 0.f, c2 = 0.f;
    float b00[4], b0p[4], b1s[4], b2s[4];  // lane-0-meaningful biases
    float sOld0[4] = {0, 0, 0, 0}, sOld1[4] = {0, 0, 0, 0}, sOld2[4] = {0, 0, 0, 0};

    // ---- Encoder layer 0: h=c=0 -> Whh zero, f-gate dead. Publish ph0. ----
    {
      float s0 = 0.f, s1 = 0.f, s2 = 0.f, s3 = 0.f;
      if (lane < F) {
        const float xv = p.x[lane];
        s0 = p.eW0[(size_t)(0 * H + r) * F + lane] * xv;
        s1 = p.eW0[(size_t)(1 * H + r) * F + lane] * xv;
        s2 = p.eW0[(size_t)(2 * H + r) * F + lane] * xv;
        s3 = p.eW0[(size_t)(3 * H + r) * F + lane] * xv;
      }
      float4 v = wredsum4(make_float4(s0, s1, s2, s3));
      if (lane == 0) {
        const float* bi_ = p.ebih + r;
        const float* bh_ = p.ebhh + r;
        float cn = sigm(v.x + bi_[0] + bh_[0]) * tanh_f(v.z + bi_[2 * H] + bh_[2 * H]);
        c0 = cn;
        pput4(par, 0, r, sigm(v.w + bi_[3 * H] + bh_[3 * H]) * tanh_f(cn));
      }
    }

    // ---- Build sM while other blocks finish enc0 (input-independent) ----
    {
      float4 mA[4], mB[4];
#pragma unroll
      for (int g = 0; g < 4; ++g) {
        mA[g] = make_float4(0.f, 0.f, 0.f, 0.f);
        mB[g] = make_float4(0.f, 0.f, 0.f, 0.f);
      }
      for (int f = 0; f < F; ++f) {
        const float* q = p.outW + (size_t)f * (2 * H) + lane * 8;
        const float4 oa = *(const float4*)q;
        const float4 ob = *(const float4*)(q + 4);
#pragma unroll
        for (int g = 0; g < 4; ++g) {
          const float wf = p.dW0[(size_t)(g * H + r) * (H + F) + f];
          mA[g].x += wf * oa.x; mA[g].y += wf * oa.y; mA[g].z += wf * oa.z; mA[g].w += wf * oa.w;
          mB[g].x += wf * ob.x; mB[g].y += wf * ob.y; mB[g].z += wf * ob.z; mB[g].w += wf * ob.w;
        }
      }
#pragma unroll
      for (int g = 0; g < 4; ++g) {
        *(float4*)(sM + (w * 4 + g) * H + lane * 8)     = mA[g];
        *(float4*)(sM + (w * 4 + g) * H + lane * 8 + 4) = mB[g];
      }
    }
#pragma unroll
    for (int g = 0; g < 4; ++g) {
      b1s[g] = p.dbih[4 * H + g * H + r] + p.dbhh[4 * H + g * H + r];
      b2s[g] = p.dbih[8 * H + g * H + r] + p.dbhh[8 * H + g * H + r];
    }

    // ---- Encoder layer 1. h0_enc stays in REGISTERS (aE0/aE1) for t=0 S0. ----
    float4 aE0, aE1;
    {
      W8 wt = ldw_g(p.eW1, r, lane);  // prefetch before poll (R0-validated order)
      poll8(g_hs[sh][par][0], lane, aE0, aE1);
      float s[4] = {0.f, 0.f, 0.f, 0.f};
      fma8(wt, aE0, aE1, s);
      float4 v = wredsum4(make_float4(s[0], s[1], s[2], s[3]));
      if (lane == 0) {
        const float* bi_ = p.ebih + 4 * H + r;
        const float* bh_ = p.ebhh + 4 * H + r;
        float cn = sigm(v.x + bi_[0] + bh_[0]) * tanh_f(v.z + bi_[2 * H] + bh_[2 * H]);
        c1 = cn;
        pput4(par, 1, r, sigm(v.w + bi_[3 * H] + bh_[3 * H]) * tanh_f(cn));
      }
    }

    // ---- Encoder layer 2 -> enc_out; extra: sOld1 = Whh1@h1_enc (for S1(0)) ----
    {
      W8 wt  = ldw_g(p.eW2, r, lane);
      W8 wh1 = ldw_g(p.dWhh + (size_t)4 * H * H, r, lane);
      float4 a0, a1;
      poll8(g_hs[sh][par][1], lane, a0, a1);
      float s[4] = {0.f, 0.f, 0.f, 0.f};
      fma8(wt, a0, a1, s);
      float4 v = wredsum4(make_float4(s[0], s[1], s[2], s[3]));
      if (lane == 0) {
        const float* bi_ = p.ebih + 8 * H + r;
        const float* bh_ = p.ebhh + 8 * H + r;
        float cn = sigm(v.x + bi_[0] + bh_[0]) * tanh_f(v.z + bi_[2 * H] + bh_[2 * H]);
        c2 = cn;
        pput4(par, 2, r, sigm(v.w + bi_[3 * H] + bh_[3 * H]) * tanh_f(cn));
      }
      fma8(wh1, a0, a1, sOld1);
    }

    // ---- Setup: e0/e1 in regs; y_e; base0 constants; sOld2 = Whh2@enc ----
    {
      W8 wh2 = ldw_g(p.dWhh + (size_t)8 * H * H, r, lane);
      float4 e0, e1;
      poll8(g_hs[sh][par][2], lane, e0, e1);
      for (int j = w; j < F; j += NW) {  // y_e rows -> sYe (needed for b0p fold)
        const float* q = p.outW + (size_t)j * (2 * H) + H + lane * 8;
        float4 w0 = *(const float4*)q;
        float4 w1 = *(const float4*)(q + 4);
        float s = w0.x * e0.x + w0.y * e0.y + w0.z * e0.z + w0.w * e0.w
                + w1.x * e1.x + w1.y * e1.y + w1.z * e1.z + w1.w * e1.w;
        s = wredsum1(s);
        if (lane == 0) sYe[j] = s + p.outb[j];
      }
      {  // enc part of base0 (unaligned dW0 cols F..F+511 -> scalar)
        float sg[4];
#pragma unroll
        for (int g = 0; g < 4; ++g) {
          const float* q = p.dW0 + (size_t)(g * H + r) * (H + F) + F + lane * 8;
          sg[g] = q[0] * e0.x + q[1] * e0.y + q[2] * e0.z + q[3] * e0.w
                + q[4] * e1.x + q[5] * e1.y + q[6] * e1.z + q[7] * e1.w;
        }
        float4 v = wredsum4(make_float4(sg[0], sg[1], sg[2], sg[3]));
        if (lane == 0) {
          b0p[0] = v.x + p.dbih[0 * H + r] + p.dbhh[0 * H + r];
          b0p[1] = v.y + p.dbih[1 * H + r] + p.dbhh[1 * H + r];
          b0p[2] = v.z + p.dbih[2 * H + r] + p.dbhh[2 * H + r];
          b0p[3] = v.w + p.dbih[3 * H + r] + p.dbhh[3 * H + r];
        }
      }
      {  // prev_y part -> b00 (t=0 constant)
        float f0 = 0.f, f1 = 0.f, f2 = 0.f, f3 = 0.f;
        if (lane < F) {
          const float yv = p.py[lane];
          f0 = p.dW0[(size_t)(0 * H + r) * (H + F) + lane] * yv;
          f1 = p.dW0[(size_t)(1 * H + r) * (H + F) + lane] * yv;
          f2 = p.dW0[(size_t)(2 * H + r) * (H + F) + lane] * yv;
          f3 = p.dW0[(size_t)(3 * H + r) * (H + F) + lane] * yv;
        }
        float4 v = wredsum4(make_float4(f0, f1, f2, f3));
        if (lane == 0) {
          b00[0] = b0p[0] + v.x; b00[1] = b0p[1] + v.y;
          b00[2] = b0p[2] + v.z; b00[3] = b0p[3] + v.w;
        }
      }
      __syncthreads();  // sYe visible (also orders sM writes before reads)
      {  // fold dW0[:,:F] @ y_e into b0p (t>=1 constant)
        float f0 = 0.f, f1 = 0.f, f2 = 0.f, f3 = 0.f;
        if (lane < F) {
          const float yv = sYe[lane];
          f0 = p.dW0[(size_t)(0 * H + r) * (H + F) + lane] * yv;
          f1 = p.dW0[(size_t)(1 * H + r) * (H + F) + lane] * yv;
          f2 = p.dW0[(size_t)(2 * H + r) * (H + F) + lane] * yv;
          f3 = p.dW0[(size_t)(3 * H + r) * (H + F) + lane] * yv;
        }
        float4 v = wredsum4(make_float4(f0, f1, f2, f3));
        if (lane == 0) {
          b0p[0] += v.x; b0p[1] += v.y; b0p[2] += v.z; b0p[3] += v.w;
        }
      }
      fma8(wh2, e0, e1, sOld2);
    }

    // ---- Decoder t=0 S0: Whh0 @ h0_enc (aE regs) + b00. No poll. ----
    {
      W8 wh0 = ldw_g(p.dWhh, r, lane);
      float s[4] = {0.f, 0.f, 0.f, 0.f};
      fma8(wh0, aE0, aE1, s);
      float4 v = wredsum4(make_float4(s[0], s[1], s[2], s[3]));
      if (lane == 0) pput4(par, phS0(0), r, cellup(v, b00, c0));
    }

    // ---- Decoder main loop: BARRIER-FREE. 1 per-lane poll + 1 critical
    //      matvec per phase; waves fully independent. ----
    for (int t = 0; t < T; ++t) {
      float4 a0, a1;
      if (t >= 1) {  // S0: crit = M(LDS)@h2(t-1) + sOld0 + b0p
        W8 wh2 = ldw_g(p.dWhh + (size_t)8 * H * H, r, lane);  // prefetch (extra)
        poll8(g_hs[sh][par][phS2(t - 1)], lane, a0, a1);
        W8 wm = ldw_lds(sM, w, lane);
        float s[4] = {sOld0[0], sOld0[1], sOld0[2], sOld0[3]};
        fma8(wm, a0, a1, s);
        float4 v = wredsum4(make_float4(s[0], s[1], s[2], s[3]));
        if (lane == 0) pput4(par, phS0(t), r, cellup(v, b0p, c0));
        sOld2[0] = sOld2[1] = sOld2[2] = sOld2[3] = 0.f;
        fma8(wh2, a0, a1, sOld2);  // off-critical: for S2(t)
      }

      {  // S1: crit = dW1@h0(t) + sOld1; extra = Whh0@h0(t) -> sOld0 for S0(t+1)
        W8 wi  = ldw_g(p.dW1, r, lane);   // crit weights in flight during poll
        W8 wh0 = ldw_g(p.dWhh, r, lane);
        poll8(g_hs[sh][par][phS0(t)], lane, a0, a1);
        float s[4] = {sOld1[0], sOld1[1], sOld1[2], sOld1[3]};
        fma8(wi, a0, a1, s);
        float4 v = wredsum4(make_float4(s[0], s[1], s[2], s[3]));
        if (lane == 0) pput4(par, phS1(t), r, cellup(v, b1s, c1));
        sOld0[0] = sOld0[1] = sOld0[2] = sOld0[3] = 0.f;
        fma8(wh0, a0, a1, sOld0);
      }
      {  // S2: crit = dW2@h1(t) + sOld2; extra = Whh1@h1(t) -> sOld1 for S1(t+1)
        W8 wi  = ldw_g(p.dW2, r, lane);
        W8 wh1 = ldw_g(p.dWhh + (size_t)4 * H * H, r, lane);
        poll8(g_hs[sh][par][phS1(t)], lane, a0, a1);
        float s[4] = {sOld2[0], sOld2[1], sOld2[2], sOld2[3]};
        fma8(wi, a0, a1, s);
        float4 v = wredsum4(make_float4(s[0], s[1], s[2], s[3]));
        if (lane == 0) pput4(par, phS2(t), r, cellup(v, b2s, c2));
        sOld1[0] = sOld1[1] = sOld1[2] = sOld1[3] = 0.f;
        fma8(wh1, a0, a1, sOld1);
      }
    }

    // ---- Tail: re-poison OWN 4 rows of the OTHER bank for the next
    //      dispatch (that bank belongs to dispatch N-1, fully completed ->
    //      no consumed-before-reset race). ----
    {
      const int r0 = blockIdx.x * NW;  // rows r0..r0+3, 16B-aligned
      const float4 z4 = make_float4(0.f, 0.f, 0.f, 0.f);
      for (int idx = threadIdx.x; idx < KR * PH; idx += NT)
        *(float4*)&g_hs[idx / PH][par ^ 1][idx % PH][r0] = z4;
    }
  }
}

extern "C" void kernel_launch(void* const* d_in, const int* in_sizes, int n_in,
                              void* d_out, int out_size, void* d_ws, size_t ws_size,
                              hipStream_t stream) {
  P p;
  p.x    = (const float*)d_in[0];
  p.py   = (const float*)d_in[1];
  p.eW0  = (const float*)d_in[2];
  p.eW1  = (const float*)d_in[3];
  p.eW2  = (const float*)d_in[4];
  // d_in[5] enc_Whh: unused (encoder runs one step from h=0)
  p.ebih = (const float*)d_in[6];
  p.ebhh = (const float*)d_in[7];
  // d_in[8..10] attn_W/attn_b/v_W: unused (softmax over length-1 axis == 1)
  p.dW0  = (const float*)d_in[11];
  p.dW1  = (const float*)d_in[12];
  p.dW2  = (const float*)d_in[13];
  p.dWhh = (const float*)d_in[14];
  p.dbih = (const float*)d_in[15];
  p.dbhh = (const float*)d_in[16];
  p.outW = (const float*)d_in[17];
  p.outb = (const float*)d_in[18];
  p.out  = (float*)d_out;

  hipLaunchKernelGGL(k_flow, dim3(NB), dim3(NT), 0, stream, p);
}

// Round 8
// 307.649 us; speedup vs baseline: 1.6655x; 1.6655x over previous
//
#include <hip/hip_runtime.h>
#include <cstddef>

constexpr int H  = 512;   // hidden
constexpr int F  = 21;    // features
constexpr int T  = 28;    // output steps
constexpr int PB = 128;   // producer blocks (best-known geometry)
constexpr int NB = PB + 1;// + 1 dedicated y-writer block
constexpr int NT = 256;   // 4 waves/block -> 512 producer waves, 1 row/wave
constexpr int NW = NT / 64;
constexpr int KR = 4;     // poll-target replicas (LLC line sharding, R5: +2%)
constexpr int PH = 3 + 3 * T;  // 87 step-unique phase arrays

#define SCOPE_AGENT __HIP_MEMORY_SCOPE_AGENT

// R8 = exact revert to R6 (best measured: 205us rocprof).
// Protocol: SENTINEL (slot = fp32, +0.0f = empty; every published value is
// sigm*tanh of a nontrivial dot -> +0.0f with prob ~0). Publish = plain
// agent-scope store to KR shard replicas (consumer block b polls replica
// b&3 only). Phase arrays are STEP-UNIQUE (87). Consumers block-stage via
// one 8B load per thread + LDS + one barrier (R7 proved per-lane direct
// poll is 2x WORSE: 4x poll traffic). Re-poison: bank parity; each block
// zeroes its own rows of the other bank at end (prev dispatch complete ->
// no race). First dispatch reads .bss zeros = sentinel.
// DO-NOT-REINTRODUCE list (all measured worse): tagged 8B slots (217),
// counter-gated detect (373), stale-pipelined poll (263), reg-crit-weights
// + post-poll extras (230), per-lane direct poll (413).
__device__ float g_hs[KR][2][PH][H];
__device__ unsigned g_epoch;

// phase ids: enc_h0=0, enc_h1=1, enc_out=2, S0(t)=3+3t, S1(t)=4+3t, S2(t)=5+3t
__device__ __forceinline__ int phS0(int t) { return 3 + 3 * t; }
__device__ __forceinline__ int phS1(int t) { return 4 + 3 * t; }
__device__ __forceinline__ int phS2(int t) { return 5 + 3 * t; }

struct P {
  const float *x, *py, *eW0, *eW1, *eW2, *ebih, *ebhh;
  const float *dW0, *dW1, *dW2, *dWhh, *dbih, *dbhh, *outW, *outb;
  float* out;
};

__device__ __forceinline__ float sigm(float v)  { return 1.0f / (1.0f + __expf(-v)); }
__device__ __forceinline__ float tanh_f(float v){ return 1.0f - 2.0f / (__expf(2.0f * v) + 1.0f); }

__device__ __forceinline__ float4 wredsum4(float4 v) {
#pragma unroll
  for (int off = 32; off > 0; off >>= 1) {
    v.x += __shfl_xor(v.x, off, 64);
    v.y += __shfl_xor(v.y, off, 64);
    v.z += __shfl_xor(v.z, off, 64);
    v.w += __shfl_xor(v.w, off, 64);
  }
  return v;
}
__device__ __forceinline__ float wredsum1(float v) {
#pragma unroll
  for (int off = 32; off > 0; off >>= 1) v += __shfl_xor(v, off, 64);
  return v;
}

// Publish one row value to all KR shard replicas of phase ph (bank par).
// Plain relaxed agent-scope stores: write-through to the coherence point,
// no RMW; consumer of shard k waits only on copy k.
__device__ __forceinline__ void pput4(int par, int ph, int r, float v) {
#pragma unroll
  for (int k = 0; k < KR; ++k)
    __hip_atomic_store(&g_hs[k][par][ph][r], v, __ATOMIC_RELAXED, SCOPE_AGENT);
}

// Cooperative staged poll -> LDS: thread i owns rows {2i, 2i+1} via ONE 8B
// agent-scope load per round (fresh value each round — R3 lesson). The two
// 4B halves are independent rows; no pairwise atomicity needed. Single
// trailing barrier.
__device__ __forceinline__ void stagev(const float* __restrict__ A,
                                       float* __restrict__ dst) {
  const int i = threadIdx.x;
  const unsigned long long* q = (const unsigned long long*)A + i;
  unsigned long long v = __hip_atomic_load(q, __ATOMIC_RELAXED, SCOPE_AGENT);
  int guard = 0;
  while (((unsigned)v == 0u || (unsigned)(v >> 32) == 0u) &&
         ++guard < (1 << 20)) {
    v = __hip_atomic_load(q, __ATOMIC_RELAXED, SCOPE_AGENT);
  }
  *(float2*)(dst + 2 * i) =
      make_float2(__uint_as_float((unsigned)v), __uint_as_float((unsigned)(v >> 32)));
  __syncthreads();
}

// 4-gate weight fragment block: 8 float4 = 128B/lane per matrix row-set.
struct W8 { float4 a[4]; float4 b[4]; };

__device__ __forceinline__ W8 ldw_g(const float* __restrict__ W, int r, int lane) {
  W8 o;
#pragma unroll
  for (int g = 0; g < 4; ++g) {
    const float* q = W + (size_t)(g * H + r) * H + lane * 8;
    o.a[g] = *(const float4*)q;
    o.b[g] = *(const float4*)(q + 4);
  }
  return o;
}
__device__ __forceinline__ W8 ldw_lds(const float* sM, int w, int lane) {
  W8 o;
#pragma unroll
  for (int g = 0; g < 4; ++g) {
    const float* q = sM + (w * 4 + g) * H + lane * 8;
    o.a[g] = *(const float4*)q;
    o.b[g] = *(const float4*)(q + 4);
  }
  return o;
}
__device__ __forceinline__ void fma8(const W8& wt, const float4& x0, const float4& x1,
                                     float s[4]) {
#pragma unroll
  for (int g = 0; g < 4; ++g) {
    s[g] += wt.a[g].x * x0.x + wt.a[g].y * x0.y + wt.a[g].z * x0.z + wt.a[g].w * x0.w
          + wt.b[g].x * x1.x + wt.b[g].y * x1.y + wt.b[g].z * x1.z + wt.b[g].w * x1.w;
  }
}

__device__ __forceinline__ float cellup(const float4& v, const float b[4], float& c) {
  float cn = sigm(v.y + b[1]) * c + sigm(v.x + b[0]) * tanh_f(v.z + b[2]);
  c = cn;
  return sigm(v.w + b[3]) * tanh_f(cn);
}

__device__ __forceinline__ void write_y_frag(const P& p, int trow, int w, int lane,
                                             const float4& h0, const float4& h1,
                                             const float* sYe) {
  for (int j = w; j < F; j += NW) {
    const float* q = p.outW + (size_t)j * (2 * H) + lane * 8;
    float4 w0 = *(const float4*)q;
    float4 w1 = *(const float4*)(q + 4);
    float s = w0.x * h0.x + w0.y * h0.y + w0.z * h0.z + w0.w * h0.w
            + w1.x * h1.x + w1.y * h1.y + w1.z * h1.z + w1.w * h1.w;
    s = wredsum1(s);
    if (lane == 0) p.out[trow * F + j] = s + sYe[j];
  }
}

__global__ __launch_bounds__(NT, 1)
void k_flow(P p) {
  const int lane = threadIdx.x & 63;
  const int w    = threadIdx.x >> 6;
  const int sh   = blockIdx.x & (KR - 1);   // this block's poll shard
  const unsigned ep =
      __hip_atomic_load(&g_epoch, __ATOMIC_RELAXED, SCOPE_AGENT);
  const int par = (int)(ep & 1u);           // active slot bank this dispatch

  __shared__ float sM[NW * 4 * H];   // 32 KB: producer rows of M = dW0[:,:F]@outW_h
  __shared__ float sBuf[2][H];       // 4 KB: double-buffered staged vector
  __shared__ float senc[H];          // persistent encoder output
  __shared__ float sYe[F + 3];       // y_e = outW_e@enc + outb

  if (blockIdx.x == PB) {
    // ================= Dedicated y-writer block (off critical path) ========
    stagev(g_hs[sh][par][2], senc);
    {
      float4 e0 = *(const float4*)(senc + lane * 8);
      float4 e1 = *(const float4*)(senc + lane * 8 + 4);
      for (int j = w; j < F; j += NW) {
        const float* q = p.outW + (size_t)j * (2 * H) + H + lane * 8;
        float4 w0 = *(const float4*)q;
        float4 w1 = *(const float4*)(q + 4);
        float s = w0.x * e0.x + w0.y * e0.y + w0.z * e0.z + w0.w * e0.w
                + w1.x * e1.x + w1.y * e1.y + w1.z * e1.z + w1.w * e1.w;
        s = wredsum1(s);
        if (lane == 0) sYe[j] = s + p.outb[j];
      }
      __syncthreads();
    }
    for (int t = 0; t < T; ++t) {
      float* xb = sBuf[t & 1];
      stagev(g_hs[sh][par][phS2(t)], xb);  // h2(t), step-unique slots
      float4 h20 = *(const float4*)(xb + lane * 8);
      float4 h21 = *(const float4*)(xb + lane * 8 + 4);
      write_y_frag(p, t, w, lane, h20, h21, sYe);
    }
    // Epoch bump: next dispatch (stream-serialized) flips the slot bank.
    if (threadIdx.x == 0)
      __hip_atomic_fetch_add(&g_epoch, 1u, __ATOMIC_RELAXED, SCOPE_AGENT);
  } else {
    // ========================= Producer blocks =============================
    const int r = blockIdx.x * NW + w;  // 1 row/wave, fixed mapping (L2 locality)

    float c0 = 0.f, c1 = 0.f, c2 = 0.f;
    float b00[4], b0p[4], b1s[4], b2s[4];  // lane-0-meaningful biases
    float sOld0[4] = {0, 0, 0, 0}, sOld1[4] = {0, 0, 0, 0}, sOld2[4] = {0, 0, 0, 0};
    int bi = 0;

    // ---- Encoder layer 0: h=c=0 -> Whh zero, f-gate dead. Publish ph0. ----
    {
      float s0 = 0.f, s1 = 0.f, s2 = 0.f, s3 = 0.f;
      if (lane < F) {
        const float xv = p.x[lane];
        s0 = p.eW0[(size_t)(0 * H + r) * F + lane] * xv;
        s1 = p.eW0[(size_t)(1 * H + r) * F + lane] * xv;
        s2 = p.eW0[(size_t)(2 * H + r) * F + lane] * xv;
        s3 = p.eW0[(size_t)(3 * H + r) * F + lane] * xv;
      }
      float4 v = wredsum4(make_float4(s0, s1, s2, s3));
      if (lane == 0) {
        const float* bi_ = p.ebih + r;
        const float* bh_ = p.ebhh + r;
        float cn = sigm(v.x + bi_[0] + bh_[0]) * tanh_f(v.z + bi_[2 * H] + bh_[2 * H]);
        c0 = cn;
        pput4(par, 0, r, sigm(v.w + bi_[3 * H] + bh_[3 * H]) * tanh_f(cn));
      }
    }

    // ---- Build sM while other blocks finish enc0 (input-independent) ----
    {
      float4 mA[4], mB[4];
#pragma unroll
      for (int g = 0; g < 4; ++g) {
        mA[g] = make_float4(0.f, 0.f, 0.f, 0.f);
        mB[g] = make_float4(0.f, 0.f, 0.f, 0.f);
      }
      for (int f = 0; f < F; ++f) {
        const float* q = p.outW + (size_t)f * (2 * H) + lane * 8;
        const float4 oa = *(const float4*)q;
        const float4 ob = *(const float4*)(q + 4);
#pragma unroll
        for (int g = 0; g < 4; ++g) {
          const float wf = p.dW0[(size_t)(g * H + r) * (H + F) + f];
          mA[g].x += wf * oa.x; mA[g].y += wf * oa.y; mA[g].z += wf * oa.z; mA[g].w += wf * oa.w;
          mB[g].x += wf * ob.x; mB[g].y += wf * ob.y; mB[g].z += wf * ob.z; mB[g].w += wf * ob.w;
        }
      }
#pragma unroll
      for (int g = 0; g < 4; ++g) {
        *(float4*)(sM + (w * 4 + g) * H + lane * 8)     = mA[g];
        *(float4*)(sM + (w * 4 + g) * H + lane * 8 + 4) = mB[g];
      }
    }
#pragma unroll
    for (int g = 0; g < 4; ++g) {
      b1s[g] = p.dbih[4 * H + g * H + r] + p.dbhh[4 * H + g * H + r];
      b2s[g] = p.dbih[8 * H + g * H + r] + p.dbhh[8 * H + g * H + r];
    }

    // ---- Encoder layer 1 (stages h0_enc into sBuf[0]; kept for decoder t=0) ----
    {
      W8 wt = ldw_g(p.eW1, r, lane);  // prefetch before poll
      stagev(g_hs[sh][par][0], sBuf[0]);
      float4 a0 = *(const float4*)(sBuf[0] + lane * 8);
      float4 a1 = *(const float4*)(sBuf[0] + lane * 8 + 4);
      float s[4] = {0.f, 0.f, 0.f, 0.f};
      fma8(wt, a0, a1, s);
      float4 v = wredsum4(make_float4(s[0], s[1], s[2], s[3]));
      if (lane == 0) {
        const float* bi_ = p.ebih + 4 * H + r;
        const float* bh_ = p.ebhh + 4 * H + r;
        float cn = sigm(v.x + bi_[0] + bh_[0]) * tanh_f(v.z + bi_[2 * H] + bh_[2 * H]);
        c1 = cn;
        pput4(par, 1, r, sigm(v.w + bi_[3 * H] + bh_[3 * H]) * tanh_f(cn));
      }
    }

    // ---- Encoder layer 2 -> enc_out; extra: sOld1 = Whh1@h1_enc (for S1(0)) ----
    {
      W8 wt  = ldw_g(p.eW2, r, lane);
      W8 wh1 = ldw_g(p.dWhh + (size_t)4 * H * H, r, lane);
      stagev(g_hs[sh][par][1], sBuf[1]);
      float4 a0 = *(const float4*)(sBuf[1] + lane * 8);
      float4 a1 = *(const float4*)(sBuf[1] + lane * 8 + 4);
      float s[4] = {0.f, 0.f, 0.f, 0.f};
      fma8(wt, a0, a1, s);
      float4 v = wredsum4(make_float4(s[0], s[1], s[2], s[3]));
      if (lane == 0) {
        const float* bi_ = p.ebih + 8 * H + r;
        const float* bh_ = p.ebhh + 8 * H + r;
        float cn = sigm(v.x + bi_[0] + bh_[0]) * tanh_f(v.z + bi_[2 * H] + bh_[2 * H]);
        c2 = cn;
        pput4(par, 2, r, sigm(v.w + bi_[3 * H] + bh_[3 * H]) * tanh_f(cn));
      }
      fma8(wh1, a0, a1, sOld1);
    }

    // ---- Setup: senc, y_e, base0 constants; extra: sOld2 = Whh2@enc ----
    {
      W8 wh2 = ldw_g(p.dWhh + (size_t)8 * H * H, r, lane);
      stagev(g_hs[sh][par][2], senc);   // senc persists (read-only afterwards)
      float4 e0 = *(const float4*)(senc + lane * 8);
      float4 e1 = *(const float4*)(senc + lane * 8 + 4);
      for (int j = w; j < F; j += NW) {  // y_e rows -> sYe (needed for b0p fold)
        const float* q = p.outW + (size_t)j * (2 * H) + H + lane * 8;
        float4 w0 = *(const float4*)q;
        float4 w1 = *(const float4*)(q + 4);
        float s = w0.x * e0.x + w0.y * e0.y + w0.z * e0.z + w0.w * e0.w
                + w1.x * e1.x + w1.y * e1.y + w1.z * e1.z + w1.w * e1.w;
        s = wredsum1(s);
        if (lane == 0) sYe[j] = s + p.outb[j];
      }
      {  // enc part of base0 (unaligned dW0 cols F..F+511 -> scalar)
        float sg[4];
#pragma unroll
        for (int g = 0; g < 4; ++g) {
          const float* q = p.dW0 + (size_t)(g * H + r) * (H + F) + F + lane * 8;
          sg[g] = q[0] * e0.x + q[1] * e0.y + q[2] * e0.z + q[3] * e0.w
                + q[4] * e1.x + q[5] * e1.y + q[6] * e1.z + q[7] * e1.w;
        }
        float4 v = wredsum4(make_float4(sg[0], sg[1], sg[2], sg[3]));
        if (lane == 0) {
          b0p[0] = v.x + p.dbih[0 * H + r] + p.dbhh[0 * H + r];
          b0p[1] = v.y + p.dbih[1 * H + r] + p.dbhh[1 * H + r];
          b0p[2] = v.z + p.dbih[2 * H + r] + p.dbhh[2 * H + r];
          b0p[3] = v.w + p.dbih[3 * H + r] + p.dbhh[3 * H + r];
        }
      }
      {  // prev_y part -> b00 (t=0 constant)
        float f0 = 0.f, f1 = 0.f, f2 = 0.f, f3 = 0.f;
        if (lane < F) {
          const float yv = p.py[lane];
          f0 = p.dW0[(size_t)(0 * H + r) * (H + F) + lane] * yv;
          f1 = p.dW0[(size_t)(1 * H + r) * (H + F) + lane] * yv;
          f2 = p.dW0[(size_t)(2 * H + r) * (H + F) + lane] * yv;
          f3 = p.dW0[(size_t)(3 * H + r) * (H + F) + lane] * yv;
        }
        float4 v = wredsum4(make_float4(f0, f1, f2, f3));
        if (lane == 0) {
          b00[0] = b0p[0] + v.x; b00[1] = b0p[1] + v.y;
          b00[2] = b0p[2] + v.z; b00[3] = b0p[3] + v.w;
        }
      }
      __syncthreads();  // sYe visible
      {  // fold dW0[:,:F] @ y_e into b0p (t>=1 constant)
        float f0 = 0.f, f1 = 0.f, f2 = 0.f, f3 = 0.f;
        if (lane < F) {
          const float yv = sYe[lane];
          f0 = p.dW0[(size_t)(0 * H + r) * (H + F) + lane] * yv;
          f1 = p.dW0[(size_t)(1 * H + r) * (H + F) + lane] * yv;
          f2 = p.dW0[(size_t)(2 * H + r) * (H + F) + lane] * yv;
          f3 = p.dW0[(size_t)(3 * H + r) * (H + F) + lane] * yv;
        }
        float4 v = wredsum4(make_float4(f0, f1, f2, f3));
        if (lane == 0) {
          b0p[0] += v.x; b0p[1] += v.y; b0p[2] += v.z; b0p[3] += v.w;
        }
      }
      fma8(wh2, e0, e1, sOld2);
    }

    // ---- Decoder t=0 S0: Whh0 @ h0_enc (still live in sBuf[0]) + b00. No poll. ----
    {
      W8 wh0 = ldw_g(p.dWhh, r, lane);
      float4 a0 = *(const float4*)(sBuf[0] + lane * 8);
      float4 a1 = *(const float4*)(sBuf[0] + lane * 8 + 4);
      float s[4] = {0.f, 0.f, 0.f, 0.f};
      fma8(wh0, a0, a1, s);
      float4 v = wredsum4(make_float4(s[0], s[1], s[2], s[3]));
      if (lane == 0) pput4(par, phS0(0), r, cellup(v, b00, c0));
    }
    __syncthreads();  // WAR: S1(0) staging overwrites sBuf[0]

    // ---- Decoder main loop: 1 poll + 1 critical matvec per phase;
    //      all 128 producer blocks perfectly symmetric every phase. ----
    for (int t = 0; t < T; ++t) {
      if (t >= 1) {  // S0: crit = M(LDS)@h2(t-1) + sOld0 + b0p
        W8 wh2 = ldw_g(p.dWhh + (size_t)8 * H * H, r, lane);  // prefetch (extra)
        stagev(g_hs[sh][par][phS2(t - 1)], sBuf[bi]);
        W8 wm = ldw_lds(sM, w, lane);
        float4 h20 = *(const float4*)(sBuf[bi] + lane * 8);
        float4 h21 = *(const float4*)(sBuf[bi] + lane * 8 + 4);
        float s[4] = {sOld0[0], sOld0[1], sOld0[2], sOld0[3]};
        fma8(wm, h20, h21, s);
        float4 v = wredsum4(make_float4(s[0], s[1], s[2], s[3]));
        if (lane == 0) pput4(par, phS0(t), r, cellup(v, b0p, c0));
        sOld2[0] = sOld2[1] = sOld2[2] = sOld2[3] = 0.f;
        fma8(wh2, h20, h21, sOld2);  // off-critical: for S2(t)
        bi ^= 1;
      }

      {  // S1: crit = dW1@h0(t) + sOld1; extra = Whh0@h0(t) -> sOld0 for S0(t+1)
        W8 wi  = ldw_g(p.dW1, r, lane);   // crit weights in flight during poll
        W8 wh0 = ldw_g(p.dWhh, r, lane);
        stagev(g_hs[sh][par][phS0(t)], sBuf[bi]);
        float4 a0 = *(const float4*)(sBuf[bi] + lane * 8);
        float4 a1 = *(const float4*)(sBuf[bi] + lane * 8 + 4);
        float s[4] = {sOld1[0], sOld1[1], sOld1[2], sOld1[3]};
        fma8(wi, a0, a1, s);
        float4 v = wredsum4(make_float4(s[0], s[1], s[2], s[3]));
        if (lane == 0) pput4(par, phS1(t), r, cellup(v, b1s, c1));
        sOld0[0] = sOld0[1] = sOld0[2] = sOld0[3] = 0.f;
        fma8(wh0, a0, a1, sOld0);
        bi ^= 1;
      }
      {  // S2: crit = dW2@h1(t) + sOld2; extra = Whh1@h1(t) -> sOld1 for S1(t+1)
        W8 wi  = ldw_g(p.dW2, r, lane);
        W8 wh1 = ldw_g(p.dWhh + (size_t)4 * H * H, r, lane);
        stagev(g_hs[sh][par][phS1(t)], sBuf[bi]);
        float4 a0 = *(const float4*)(sBuf[bi] + lane * 8);
        float4 a1 = *(const float4*)(sBuf[bi] + lane * 8 + 4);
        float s[4] = {sOld2[0], sOld2[1], sOld2[2], sOld2[3]};
        fma8(wi, a0, a1, s);
        float4 v = wredsum4(make_float4(s[0], s[1], s[2], s[3]));
        if (lane == 0) pput4(par, phS2(t), r, cellup(v, b2s, c2));
        sOld1[0] = sOld1[1] = sOld1[2] = sOld1[3] = 0.f;
        fma8(wh1, a0, a1, sOld1);
        bi ^= 1;
      }
    }

    // ---- Tail: re-poison OWN 4 rows of the OTHER bank for the next
    //      dispatch (that bank belongs to dispatch N-1, fully completed ->
    //      no consumed-before-reset race). ----
    {
      const int r0 = blockIdx.x * NW;  // rows r0..r0+3, 16B-aligned
      const float4 z4 = make_float4(0.f, 0.f, 0.f, 0.f);
      for (int idx = threadIdx.x; idx < KR * PH; idx += NT)
        *(float4*)&g_hs[idx / PH][par ^ 1][idx % PH][r0] = z4;
    }
  }
}

extern "C" void kernel_launch(void* const* d_in, const int* in_sizes, int n_in,
                              void* d_out, int out_size, void* d_ws, size_t ws_size,
                              hipStream_t stream) {
  P p;
  p.x    = (const float*)d_in[0];
  p.py   = (const float*)d_in[1];
  p.eW0  = (const float*)d_in[2];
  p.eW1  = (const float*)d_in[3];
  p.eW2  = (const float*)d_in[4];
  // d_in[5] enc_Whh: unused (encoder runs one step from h=0)
  p.ebih = (const float*)d_in[6];
  p.ebhh = (const float*)d_in[7];
  // d_in[8..10] attn_W/attn_b/v_W: unused (softmax over length-1 axis == 1)
  p.dW0  = (const float*)d_in[11];
  p.dW1  = (const float*)d_in[12];
  p.dW2  = (const float*)d_in[13];
  p.dWhh = (const float*)d_in[14];
  p.dbih = (const float*)d_in[15];
  p.dbhh = (const float*)d_in[16];
  p.outW = (const float*)d_in[17];
  p.outb = (const float*)d_in[18];
  p.out  = (float*)d_out;

  hipLaunchKernelGGL(k_flow, dim3(NB), dim3(NT), 0, stream, p);
}

// Round 9
// 297.065 us; speedup vs baseline: 1.7248x; 1.0356x over previous
//
#include <hip/hip_runtime.h>
#include <cstddef>

constexpr int H  = 512;   // hidden
constexpr int F  = 21;    // features
constexpr int T  = 28;    // output steps
constexpr int PB = 128;   // producer blocks (validated best geometry)
constexpr int NB = PB + 1;// + 1 dedicated y-writer block
constexpr int NT = 256;   // 4 waves/block -> 512 producer waves, 1 row/wave
constexpr int NW = NT / 64;
constexpr int KR = 4;     // poll-target replicas (LLC line-contention sharding)

#define SCOPE_AGENT __HIP_MEMORY_SCOPE_AGENT

// R9 = exact revert to R5, the BEST harness-verified kernel (294.5us bench).
// Bench-metric ladder (stable to ±0.6%): R5 tagged/exchange+KR4 = 294.5 <
// R6/R8 sentinel/store = 305.8/307.6 < R0/R4 = 317-319. rocprof per-dispatch
// means vary ±10% across sessions under profiling and mis-ranked R6 vs R5.
//
// Protocol: tagged slots (tag<<32)|float_bits; publish = fire-and-forget
// agent-scope exchange to KR replicas (consumer block b polls replica b&3
// only — R5's +2%); tags epoch-based: tag=(epoch<<6)+k, k=1 encoder,
// k=t+2 decoder step t; y-writer bumps g_epoch at end -> slots self-
// invalidate across graph replays, no reset pass. Tags are never zero and
// never value-dependent -> immune to the sentinel +0.0f spin hazard
// (R8 rocprof showed a 22ms guard-bounded outlier under the sentinel
// protocol; none ever observed under tags).
//
// DO-NOT-REINTRODUCE (bench-measured worse): sentinel+plain-store (306),
// counter-gated detect (373+), stale-pipelined poll (367), reg-crit-weights
// + post-poll extras (334), per-lane direct poll (512).
__device__ unsigned long long g_hp[KR][2][3][H];
__device__ unsigned long long g_hy[T][H];
__device__ unsigned g_epoch;

struct P {
  const float *x, *py, *eW0, *eW1, *eW2, *ebih, *ebhh;
  const float *dW0, *dW1, *dW2, *dWhh, *dbih, *dbhh, *outW, *outb;
  float* out;
};

__device__ __forceinline__ float sigm(float v)  { return 1.0f / (1.0f + __expf(-v)); }
__device__ __forceinline__ float tanh_f(float v){ return 1.0f - 2.0f / (__expf(2.0f * v) + 1.0f); }

__device__ __forceinline__ float4 wredsum4(float4 v) {
#pragma unroll
  for (int off = 32; off > 0; off >>= 1) {
    v.x += __shfl_xor(v.x, off, 64);
    v.y += __shfl_xor(v.y, off, 64);
    v.z += __shfl_xor(v.z, off, 64);
    v.w += __shfl_xor(v.w, off, 64);
  }
  return v;
}
__device__ __forceinline__ float wredsum1(float v) {
#pragma unroll
  for (int off = 32; off > 0; off >>= 1) v += __shfl_xor(v, off, 64);
  return v;
}

// Publish one row value to all KR replicas of slot (pb,l,r). Exchanges are
// relaxed, independent addresses -> all in flight simultaneously; the
// consumer of shard k waits only on copy k.
__device__ __forceinline__ void pputR(int pb, int l, int r, float v, unsigned tag) {
  union { float f; unsigned u; } c; c.f = v;
  unsigned long long pk = ((unsigned long long)tag << 32) | (unsigned long long)c.u;
#pragma unroll
  for (int k = 0; k < KR; ++k)
    (void)__hip_atomic_exchange(&g_hp[k][pb][l][r], pk, __ATOMIC_RELAXED, SCOPE_AGENT);
}
__device__ __forceinline__ void pput(unsigned long long* slot, float v, unsigned tag) {
  union { float f; unsigned u; } c; c.f = v;
  unsigned long long pk = ((unsigned long long)tag << 32) | (unsigned long long)c.u;
  (void)__hip_atomic_exchange(slot, pk, __ATOMIC_RELAXED, SCOPE_AGENT);
}
__device__ __forceinline__ unsigned long long tld(const unsigned long long* q) {
  return __hip_atomic_load(q, __ATOMIC_RELAXED, SCOPE_AGENT);
}
__device__ __forceinline__ float fbits(unsigned long long v) {
  union { unsigned u; float f; } c; c.u = (unsigned)v; return c.f;
}

// Cooperative staged poll -> LDS: thread i owns elements {i, i+NT}; coalesced;
// both loads in flight per attempt; FRESH values checked each iteration
// (stale-pipelined variant measured +33us — do not reintroduce);
// single trailing barrier.
__device__ __forceinline__ void stagev(const unsigned long long* __restrict__ A,
                                       unsigned wa, float* __restrict__ dst) {
  const int i = threadIdx.x;
  unsigned long long v0 = tld(A + i), v1 = tld(A + i + NT);
  int guard = 0;
  while ((((unsigned)(v0 >> 32)) != wa || ((unsigned)(v1 >> 32)) != wa) &&
         ++guard < (1 << 20)) {
    v0 = tld(A + i); v1 = tld(A + i + NT);
  }
  dst[i] = fbits(v0); dst[i + NT] = fbits(v1);
  __syncthreads();
}

// 4-gate weight fragment block: 8 float4 = 128B/lane per matrix row-set.
struct W8 { float4 a[4]; float4 b[4]; };

__device__ __forceinline__ W8 ldw_g(const float* __restrict__ W, int r, int lane) {
  W8 o;
#pragma unroll
  for (int g = 0; g < 4; ++g) {
    const float* q = W + (size_t)(g * H + r) * H + lane * 8;
    o.a[g] = *(const float4*)q;
    o.b[g] = *(const float4*)(q + 4);
  }
  return o;
}
__device__ __forceinline__ W8 ldw_lds(const float* sM, int w, int lane) {
  W8 o;
#pragma unroll
  for (int g = 0; g < 4; ++g) {
    const float* q = sM + (w * 4 + g) * H + lane * 8;
    o.a[g] = *(const float4*)q;
    o.b[g] = *(const float4*)(q + 4);
  }
  return o;
}
__device__ __forceinline__ void fma8(const W8& wt, const float4& x0, const float4& x1,
                                     float s[4]) {
#pragma unroll
  for (int g = 0; g < 4; ++g) {
    s[g] += wt.a[g].x * x0.x + wt.a[g].y * x0.y + wt.a[g].z * x0.z + wt.a[g].w * x0.w
          + wt.b[g].x * x1.x + wt.b[g].y * x1.y + wt.b[g].z * x1.z + wt.b[g].w * x1.w;
  }
}

__device__ __forceinline__ float cellup(const float4& v, const float b[4], float& c) {
  float cn = sigm(v.y + b[1]) * c + sigm(v.x + b[0]) * tanh_f(v.z + b[2]);
  c = cn;
  return sigm(v.w + b[3]) * tanh_f(cn);
}

__device__ __forceinline__ void write_y_frag(const P& p, int trow, int w, int lane,
                                             const float4& h0, const float4& h1,
                                             const float* sYe) {
  for (int j = w; j < F; j += NW) {
    const float* q = p.outW + (size_t)j * (2 * H) + lane * 8;
    float4 w0 = *(const float4*)q;
    float4 w1 = *(const float4*)(q + 4);
    float s = w0.x * h0.x + w0.y * h0.y + w0.z * h0.z + w0.w * h0.w
            + w1.x * h1.x + w1.y * h1.y + w1.z * h1.z + w1.w * h1.w;
    s = wredsum1(s);
    if (lane == 0) p.out[trow * F + j] = s + sYe[j];
  }
}

__global__ __launch_bounds__(NT, 1)
void k_flow(P p) {
  const int lane = threadIdx.x & 63;
  const int w    = threadIdx.x >> 6;
  const int sh   = blockIdx.x & (KR - 1);   // this block's poll shard
  const unsigned tg =
      __hip_atomic_load(&g_epoch, __ATOMIC_RELAXED, SCOPE_AGENT) << 6;

  __shared__ float sM[NW * 4 * H];   // 32 KB: producer rows of M = dW0[:,:F]@outW_h
  __shared__ float sBuf[2][H];       // 4 KB: double-buffered staged vector
  __shared__ float senc[H];          // persistent encoder output
  __shared__ float sYe[F + 3];       // y_e = outW_e@enc + outb

  if (blockIdx.x == PB) {
    // ================= Dedicated y-writer block (off critical path) ========
    stagev(g_hp[sh][1][2], tg + 1u, senc);
    {
      float4 e0 = *(const float4*)(senc + lane * 8);
      float4 e1 = *(const float4*)(senc + lane * 8 + 4);
      for (int j = w; j < F; j += NW) {
        const float* q = p.outW + (size_t)j * (2 * H) + H + lane * 8;
        float4 w0 = *(const float4*)q;
        float4 w1 = *(const float4*)(q + 4);
        float s = w0.x * e0.x + w0.y * e0.y + w0.z * e0.z + w0.w * e0.w
                + w1.x * e1.x + w1.y * e1.y + w1.z * e1.z + w1.w * e1.w;
        s = wredsum1(s);
        if (lane == 0) sYe[j] = s + p.outb[j];
      }
      __syncthreads();
    }
    for (int t = 0; t < T; ++t) {
      float* xb = sBuf[t & 1];
      stagev(g_hy[t], tg + (unsigned)(t + 2), xb);  // h2(t), step-unique slot
      float4 h20 = *(const float4*)(xb + lane * 8);
      float4 h21 = *(const float4*)(xb + lane * 8 + 4);
      write_y_frag(p, t, w, lane, h20, h21, sYe);
    }
    // Epoch bump: next dispatch (stream-serialized) sees fresh tags; all
    // slots from this dispatch become stale automatically. No reset pass.
    if (threadIdx.x == 0)
      __hip_atomic_fetch_add(&g_epoch, 1u, __ATOMIC_RELAXED, SCOPE_AGENT);
  } else {
    // ========================= Producer blocks =============================
    const int r = blockIdx.x * NW + w;  // 1 row/wave, fixed mapping (L2 locality)

    float c0 = 0.f, c1 = 0.f, c2 = 0.f;
    float b00[4], b0p[4], b1s[4], b2s[4];  // lane-0-meaningful biases
    float sOld0[4] = {0, 0, 0, 0}, sOld1[4] = {0, 0, 0, 0}, sOld2[4] = {0, 0, 0, 0};
    int bi = 0;

    // ---- Encoder layer 0: h=c=0 -> Whh zero, f-gate dead. Publish tg+1. ----
    {
      float s0 = 0.f, s1 = 0.f, s2 = 0.f, s3 = 0.f;
      if (lane < F) {
        const float xv = p.x[lane];
        s0 = p.eW0[(size_t)(0 * H + r) * F + lane] * xv;
        s1 = p.eW0[(size_t)(1 * H + r) * F + lane] * xv;
        s2 = p.eW0[(size_t)(2 * H + r) * F + lane] * xv;
        s3 = p.eW0[(size_t)(3 * H + r) * F + lane] * xv;
      }
      float4 v = wredsum4(make_float4(s0, s1, s2, s3));
      if (lane == 0) {
        const float* bi_ = p.ebih + r;
        const float* bh_ = p.ebhh + r;
        float cn = sigm(v.x + bi_[0] + bh_[0]) * tanh_f(v.z + bi_[2 * H] + bh_[2 * H]);
        c0 = cn;
        pputR(1, 0, r, sigm(v.w + bi_[3 * H] + bh_[3 * H]) * tanh_f(cn), tg + 1u);
      }
    }

    // ---- Build sM while other blocks finish enc0 (input-independent) ----
    {
      float4 mA[4], mB[4];
#pragma unroll
      for (int g = 0; g < 4; ++g) {
        mA[g] = make_float4(0.f, 0.f, 0.f, 0.f);
        mB[g] = make_float4(0.f, 0.f, 0.f, 0.f);
      }
      for (int f = 0; f < F; ++f) {
        const float* q = p.outW + (size_t)f * (2 * H) + lane * 8;
        const float4 oa = *(const float4*)q;
        const float4 ob = *(const float4*)(q + 4);
#pragma unroll
        for (int g = 0; g < 4; ++g) {
          const float wf = p.dW0[(size_t)(g * H + r) * (H + F) + f];
          mA[g].x += wf * oa.x; mA[g].y += wf * oa.y; mA[g].z += wf * oa.z; mA[g].w += wf * oa.w;
          mB[g].x += wf * ob.x; mB[g].y += wf * ob.y; mB[g].z += wf * ob.z; mB[g].w += wf * ob.w;
        }
      }
#pragma unroll
      for (int g = 0; g < 4; ++g) {
        *(float4*)(sM + (w * 4 + g) * H + lane * 8)     = mA[g];
        *(float4*)(sM + (w * 4 + g) * H + lane * 8 + 4) = mB[g];
      }
    }
#pragma unroll
    for (int g = 0; g < 4; ++g) {
      b1s[g] = p.dbih[4 * H + g * H + r] + p.dbhh[4 * H + g * H + r];
      b2s[g] = p.dbih[8 * H + g * H + r] + p.dbhh[8 * H + g * H + r];
    }

    // ---- Encoder layer 1 (stages h0_enc into sBuf[0]; kept for decoder t=0) ----
    {
      W8 wt = ldw_g(p.eW1, r, lane);  // prefetch before poll
      stagev(g_hp[sh][1][0], tg + 1u, sBuf[0]);
      float4 a0 = *(const float4*)(sBuf[0] + lane * 8);
      float4 a1 = *(const float4*)(sBuf[0] + lane * 8 + 4);
      float s[4] = {0.f, 0.f, 0.f, 0.f};
      fma8(wt, a0, a1, s);
      float4 v = wredsum4(make_float4(s[0], s[1], s[2], s[3]));
      if (lane == 0) {
        const float* bi_ = p.ebih + 4 * H + r;
        const float* bh_ = p.ebhh + 4 * H + r;
        float cn = sigm(v.x + bi_[0] + bh_[0]) * tanh_f(v.z + bi_[2 * H] + bh_[2 * H]);
        c1 = cn;
        pputR(1, 1, r, sigm(v.w + bi_[3 * H] + bh_[3 * H]) * tanh_f(cn), tg + 1u);
      }
    }

    // ---- Encoder layer 2 -> enc_out; extra: sOld1 = Whh1@h1_enc (for S1(0)) ----
    {
      W8 wt  = ldw_g(p.eW2, r, lane);
      W8 wh1 = ldw_g(p.dWhh + (size_t)4 * H * H, r, lane);
      stagev(g_hp[sh][1][1], tg + 1u, sBuf[1]);
      float4 a0 = *(const float4*)(sBuf[1] + lane * 8);
      float4 a1 = *(const float4*)(sBuf[1] + lane * 8 + 4);
      float s[4] = {0.f, 0.f, 0.f, 0.f};
      fma8(wt, a0, a1, s);
      float4 v = wredsum4(make_float4(s[0], s[1], s[2], s[3]));
      if (lane == 0) {
        const float* bi_ = p.ebih + 8 * H + r;
        const float* bh_ = p.ebhh + 8 * H + r;
        float cn = sigm(v.x + bi_[0] + bh_[0]) * tanh_f(v.z + bi_[2 * H] + bh_[2 * H]);
        c2 = cn;
        pputR(1, 2, r, sigm(v.w + bi_[3 * H] + bh_[3 * H]) * tanh_f(cn), tg + 1u);
      }
      fma8(wh1, a0, a1, sOld1);
    }

    // ---- Setup: senc, y_e, base0 constants; extra: sOld2 = Whh2@enc ----
    {
      W8 wh2 = ldw_g(p.dWhh + (size_t)8 * H * H, r, lane);
      stagev(g_hp[sh][1][2], tg + 1u, senc);   // senc persists (read-only after)
      float4 e0 = *(const float4*)(senc + lane * 8);
      float4 e1 = *(const float4*)(senc + lane * 8 + 4);
      for (int j = w; j < F; j += NW) {  // y_e rows -> sYe (needed for b0p fold)
        const float* q = p.outW + (size_t)j * (2 * H) + H + lane * 8;
        float4 w0 = *(const float4*)q;
        float4 w1 = *(const float4*)(q + 4);
        float s = w0.x * e0.x + w0.y * e0.y + w0.z * e0.z + w0.w * e0.w
                + w1.x * e1.x + w1.y * e1.y + w1.z * e1.z + w1.w * e1.w;
        s = wredsum1(s);
        if (lane == 0) sYe[j] = s + p.outb[j];
      }
      {  // enc part of base0 (unaligned dW0 cols F..F+511 -> scalar)
        float sg[4];
#pragma unroll
        for (int g = 0; g < 4; ++g) {
          const float* q = p.dW0 + (size_t)(g * H + r) * (H + F) + F + lane * 8;
          sg[g] = q[0] * e0.x + q[1] * e0.y + q[2] * e0.z + q[3] * e0.w
                + q[4] * e1.x + q[5] * e1.y + q[6] * e1.z + q[7] * e1.w;
        }
        float4 v = wredsum4(make_float4(sg[0], sg[1], sg[2], sg[3]));
        if (lane == 0) {
          b0p[0] = v.x + p.dbih[0 * H + r] + p.dbhh[0 * H + r];
          b0p[1] = v.y + p.dbih[1 * H + r] + p.dbhh[1 * H + r];
          b0p[2] = v.z + p.dbih[2 * H + r] + p.dbhh[2 * H + r];
          b0p[3] = v.w + p.dbih[3 * H + r] + p.dbhh[3 * H + r];
        }
      }
      {  // prev_y part -> b00 (t=0 constant)
        float f0 = 0.f, f1 = 0.f, f2 = 0.f, f3 = 0.f;
        if (lane < F) {
          const float yv = p.py[lane];
          f0 = p.dW0[(size_t)(0 * H + r) * (H + F) + lane] * yv;
          f1 = p.dW0[(size_t)(1 * H + r) * (H + F) + lane] * yv;
          f2 = p.dW0[(size_t)(2 * H + r) * (H + F) + lane] * yv;
          f3 = p.dW0[(size_t)(3 * H + r) * (H + F) + lane] * yv;
        }
        float4 v = wredsum4(make_float4(f0, f1, f2, f3));
        if (lane == 0) {
          b00[0] = b0p[0] + v.x; b00[1] = b0p[1] + v.y;
          b00[2] = b0p[2] + v.z; b00[3] = b0p[3] + v.w;
        }
      }
      __syncthreads();  // sYe visible
      {  // fold dW0[:,:F] @ y_e into b0p (t>=1 constant)
        float f0 = 0.f, f1 = 0.f, f2 = 0.f, f3 = 0.f;
        if (lane < F) {
          const float yv = sYe[lane];
          f0 = p.dW0[(size_t)(0 * H + r) * (H + F) + lane] * yv;
          f1 = p.dW0[(size_t)(1 * H + r) * (H + F) + lane] * yv;
          f2 = p.dW0[(size_t)(2 * H + r) * (H + F) + lane] * yv;
          f3 = p.dW0[(size_t)(3 * H + r) * (H + F) + lane] * yv;
        }
        float4 v = wredsum4(make_float4(f0, f1, f2, f3));
        if (lane == 0) {
          b0p[0] += v.x; b0p[1] += v.y; b0p[2] += v.z; b0p[3] += v.w;
        }
      }
      fma8(wh2, e0, e1, sOld2);
    }

    // ---- Decoder t=0 S0: Whh0 @ h0_enc (still live in sBuf[0]) + b00. No poll. ----
    {
      W8 wh0 = ldw_g(p.dWhh, r, lane);
      float4 a0 = *(const float4*)(sBuf[0] + lane * 8);
      float4 a1 = *(const float4*)(sBuf[0] + lane * 8 + 4);
      float s[4] = {0.f, 0.f, 0.f, 0.f};
      fma8(wh0, a0, a1, s);
      float4 v = wredsum4(make_float4(s[0], s[1], s[2], s[3]));
      if (lane == 0) pputR(0, 0, r, cellup(v, b00, c0), tg + 2u);
    }
    __syncthreads();  // WAR: S1(0) staging overwrites sBuf[0]

    // ---- Decoder main loop: 1 poll + 1 critical matvec per phase;
    //      all 128 producer blocks perfectly symmetric every phase. ----
    for (int t = 0; t < T; ++t) {
      const int pb = t & 1, ob = pb ^ 1;
      const unsigned wn = tg + (unsigned)(t + 2);
      const unsigned wo = wn - 1u;

      if (t >= 1) {  // S0: crit = M(LDS)@h2(t-1) + sOld0 + b0p
        W8 wh2 = ldw_g(p.dWhh + (size_t)8 * H * H, r, lane);  // prefetch (extra)
        stagev(g_hp[sh][ob][2], wo, sBuf[bi]);
        W8 wm = ldw_lds(sM, w, lane);
        float4 h20 = *(const float4*)(sBuf[bi] + lane * 8);
        float4 h21 = *(const float4*)(sBuf[bi] + lane * 8 + 4);
        float s[4] = {sOld0[0], sOld0[1], sOld0[2], sOld0[3]};
        fma8(wm, h20, h21, s);
        float4 v = wredsum4(make_float4(s[0], s[1], s[2], s[3]));
        if (lane == 0) pputR(pb, 0, r, cellup(v, b0p, c0), wn);
        sOld2[0] = sOld2[1] = sOld2[2] = sOld2[3] = 0.f;
        fma8(wh2, h20, h21, sOld2);  // off-critical: for S2(t)
        bi ^= 1;
      }

      {  // S1: crit = dW1@h0(t) + sOld1; extra = Whh0@h0(t) -> sOld0 for S0(t+1)
        W8 wi  = ldw_g(p.dW1, r, lane);   // crit weights in flight during poll
        W8 wh0 = ldw_g(p.dWhh, r, lane);
        stagev(g_hp[sh][pb][0], wn, sBuf[bi]);
        float4 a0 = *(const float4*)(sBuf[bi] + lane * 8);
        float4 a1 = *(const float4*)(sBuf[bi] + lane * 8 + 4);
        float s[4] = {sOld1[0], sOld1[1], sOld1[2], sOld1[3]};
        fma8(wi, a0, a1, s);
        float4 v = wredsum4(make_float4(s[0], s[1], s[2], s[3]));
        if (lane == 0) pputR(pb, 1, r, cellup(v, b1s, c1), wn);
        sOld0[0] = sOld0[1] = sOld0[2] = sOld0[3] = 0.f;
        fma8(wh0, a0, a1, sOld0);
        bi ^= 1;
      }
      {  // S2: crit = dW2@h1(t) + sOld2; extra = Whh1@h1(t) -> sOld1 for S1(t+1)
        W8 wi  = ldw_g(p.dW2, r, lane);
        W8 wh1 = ldw_g(p.dWhh + (size_t)4 * H * H, r, lane);
        stagev(g_hp[sh][pb][1], wn, sBuf[bi]);
        float4 a0 = *(const float4*)(sBuf[bi] + lane * 8);
        float4 a1 = *(const float4*)(sBuf[bi] + lane * 8 + 4);
        float s[4] = {sOld2[0], sOld2[1], sOld2[2], sOld2[3]};
        fma8(wi, a0, a1, s);
        float4 v = wredsum4(make_float4(s[0], s[1], s[2], s[3]));
        if (lane == 0) {
          float hv = cellup(v, b2s, c2);
          pputR(pb, 2, r, hv, wn);         // main chain first (all shards)
          pput(&g_hy[t][r], hv, wn);       // y-writer copy (step-unique slot)
        }
        sOld1[0] = sOld1[1] = sOld1[2] = sOld1[3] = 0.f;
        fma8(wh1, a0, a1, sOld1);
        bi ^= 1;
      }
    }
    // Producers just exit: epoch tags make stale slots harmless next replay.
  }
}

extern "C" void kernel_launch(void* const* d_in, const int* in_sizes, int n_in,
                              void* d_out, int out_size, void* d_ws, size_t ws_size,
                              hipStream_t stream) {
  P p;
  p.x    = (const float*)d_in[0];
  p.py   = (const float*)d_in[1];
  p.eW0  = (const float*)d_in[2];
  p.eW1  = (const float*)d_in[3];
  p.eW2  = (const float*)d_in[4];
  // d_in[5] enc_Whh: unused (encoder runs one step from h=0)
  p.ebih = (const float*)d_in[6];
  p.ebhh = (const float*)d_in[7];
  // d_in[8..10] attn_W/attn_b/v_W: unused (softmax over length-1 axis == 1)
  p.dW0  = (const float*)d_in[11];
  p.dW1  = (const float*)d_in[12];
  p.dW2  = (const float*)d_in[13];
  p.dWhh = (const float*)d_in[14];
  p.dbih = (const float*)d_in[15];
  p.dbhh = (const float*)d_in[16];
  p.outW = (const float*)d_in[17];
  p.outb = (const float*)d_in[18];
  p.out  = (float*)d_out;

  hipLaunchKernelGGL(k_flow, dim3(NB), dim3(NT), 0, stream, p);
}